// Round 4
// baseline (275.338 us; speedup 1.0000x reference)
//
#include <hip/hip_runtime.h>

// SpecNCutout: out = select(mask, mean(x), x)
// x: (B=128, H=256, W=1024, C=1) fp32. mask = union of 5 clipped rects/batch.
//
// R4 = R3 with compile fix: __builtin_nontemporal_* needs a native clang
// vector type, not HIP_vector_type<float,4>.
//
// Structure (minimum HBM traffic = 256 MiB):
//   1. copyreduce: out = x (nontemporal streaming copy) + block partial sums.
//      The copy rides along the mandatory full read for the mean.
//   2. holefill: every block re-reduces the 2048 partials (8 KiB, L2-hot),
//      then paints mean into the hole rects only (~40 MiB writes, no reads).

#define BB 128
#define HH 256
#define WW 1024
#define N_HOLES 5
#define HOLE_MINW (WW / 10)   // 102
#define HOLE_MINH (HH / 10)   // 25
#define N_ELEM (BB * HH * WW) // 33554432
#define RED_BLOCKS 2048
#define MAXSPAN 104                         // max hole row span (<=101) padded
#define VROWS (BB * N_HOLES * MAXSPAN)      // 66560 virtual hole-rows

typedef float f4v __attribute__((ext_vector_type(4)));

__global__ __launch_bounds__(256) void copyreduce_kernel(
    const float* __restrict__ x, float* __restrict__ out,
    float* __restrict__ partials) {
  int tid = blockIdx.x * blockDim.x + threadIdx.x;
  int stride = gridDim.x * blockDim.x;          // 524288
  const f4v* x4 = (const f4v*)x;
  f4v* out4 = (f4v*)out;
  const int n4 = N_ELEM / 4;                    // 8388608
  float s = 0.0f;
  for (int i = tid; i < n4; i += stride) {      // 16 iters
    f4v v = __builtin_nontemporal_load(&x4[i]);
    __builtin_nontemporal_store(v, &out4[i]);
    s += (v.x + v.y) + (v.z + v.w);
  }
  #pragma unroll
  for (int off = 32; off > 0; off >>= 1) s += __shfl_down(s, off, 64);
  __shared__ float wsum[4];
  int lane = threadIdx.x & 63;
  int wave = threadIdx.x >> 6;
  if (lane == 0) wsum[wave] = s;
  __syncthreads();
  if (threadIdx.x == 0)
    partials[blockIdx.x] = (wsum[0] + wsum[1]) + (wsum[2] + wsum[3]);
}

__global__ __launch_bounds__(256) void holefill_kernel(
    const int* __restrict__ xs, const int* __restrict__ ys,
    const int* __restrict__ xs_w_raw, const int* __restrict__ ys_h_raw,
    const float* __restrict__ act_rand,
    const float* __restrict__ partials,
    float* __restrict__ out) {
  // Every block computes the mean from the 2048 partials (L2-hot, ~8 KiB).
  float s = 0.0f;
  for (int i = threadIdx.x; i < RED_BLOCKS; i += 256) s += partials[i];
  #pragma unroll
  for (int off = 32; off > 0; off >>= 1) s += __shfl_down(s, off, 64);
  __shared__ float wsum[4];
  __shared__ float smean;
  int lane = threadIdx.x & 63;
  int wave = threadIdx.x >> 6;
  if (lane == 0) wsum[wave] = s;
  __syncthreads();
  if (threadIdx.x == 0) {
    float t = (wsum[0] + wsum[1]) + (wsum[2] + wsum[3]);
    smean = t * (1.0f / (float)N_ELEM);
  }
  __syncthreads();
  float mean = smean;

  // Grid-stride over virtual hole-rows: v -> (b, n, r).
  for (int v = blockIdx.x; v < VROWS; v += gridDim.x) {
    int b = v / (N_HOLES * MAXSPAN);
    int rem = v - b * (N_HOLES * MAXSPAN);
    int n = rem / MAXSPAN;
    int r = rem - n * MAXSPAN;
    int base = b * N_HOLES + n;

    int cx = xs[base];
    int cy = ys[base];
    int hw = (xs_w_raw[base] + HOLE_MINW) >> 1;  // xs_w // 2
    int hh = (ys_h_raw[base] + HOLE_MINH) >> 1;  // ys_h // 2
    int ys_s = min(max(cy - hh, 0), HH - 2);
    int ys_e = min(max(cy + hh, 1), HH - 1);
    int xs_s = min(max(cx - hw, 0), WW - 2);
    int xs_e = min(max(cx + hw, 1), WW - 1);
    bool act = act_rand[base] < 1.0f;            // PROB = 1.0

    int h = ys_s + r;
    if (!act || h > ys_e) continue;

    long rowbase = ((long)b * HH + h) * WW;
    // width <= 409; 256 threads x 2 covers it
    int w = xs_s + (int)threadIdx.x;
    if (w <= xs_e) out[rowbase + w] = mean;
    w += 256;
    if (w <= xs_e) out[rowbase + w] = mean;
  }
}

extern "C" void kernel_launch(void* const* d_in, const int* in_sizes, int n_in,
                              void* d_out, int out_size, void* d_ws, size_t ws_size,
                              hipStream_t stream) {
  const float* x        = (const float*)d_in[0];
  const int* xs         = (const int*)d_in[1];
  const int* ys         = (const int*)d_in[2];
  const int* xs_w_raw   = (const int*)d_in[3];
  const int* ys_h_raw   = (const int*)d_in[4];
  const float* act_rand = (const float*)d_in[5];
  float* out = (float*)d_out;
  float* partials = (float*)d_ws;                // RED_BLOCKS floats

  copyreduce_kernel<<<RED_BLOCKS, 256, 0, stream>>>(x, out, partials);
  holefill_kernel<<<RED_BLOCKS, 256, 0, stream>>>(xs, ys, xs_w_raw, ys_h_raw,
                                                  act_rand, partials, out);
}